// Round 9
// baseline (35.221 us; speedup 1.0000x reference)
//
#include <hip/hip_runtime.h>

// InitMotionParams: out[p,n,i] = sum_j R(p,n)[i,j]*means[p,j] + T(p,n)[i]
// R = cont_6d_to_rmat(sum_k softmax(coefs)[p,k] * motion_rots[k,ts[n],:])
// T = sum_k softmax(coefs)[p,k] * motion_transls[k,ts[n],:]
//
// Round-9 structure: LDS-shared softmax + maximal wave split.
//  - BLK=512 (8 waves), 64 gaussians/block, wave q owns slice q ONLY ->
//    shortest per-wave chain; 6250 blocks = 48.8 waves/SIMD supplied.
//  - Wave 0 computes softmax for the block's 64 gaussians (lane<->gaussian)
//    and shares w via LDS: kills the 4x redundant exp+coef-load chains of
//    rounds 6/8 (softmax was ~80/380 VALU instrs per thread, x4 per gaussian).
//  - LDS layout transposed wp[kpair][lane] (f32x2): ds_read/write_b64 at
//    lane*8 stride = canonical conflict-free pattern; DS returns in-order ->
//    fine-grained lgkmcnt waits (vs SMEM drain-to-zero).
//  - Table stays uniform s_load via readfirstlane slice id (round-4 lesson:
//    lane-dependent table addressing kills s_load, SGPR 96->32, 3x slower).
//  - NO MFMA: Gram-Schmidt amplifies operand error by 1/|a2p| (min ~4e-4
//    over 3.2M samples); bf16 operands would fail by orders of magnitude.
//  - No forced launch_bounds min-waves (round-2 spill lesson); GPT=1
//    (round-7 remat lesson).
// Softmax: no max-subtraction (inputs ~N(0,1)); 1/sum folded only into the
// translation (Gram-Schmidt is scale-invariant in the weights).

constexpr int KK    = 20;
constexpr int BB    = 8;
constexpr int BLK   = 64 * BB;   // 512: one wave per timestep slice
constexpr int GPB   = 64;        // gaussians per block (1 per lane)
constexpr int SLICE = 9 * KK;    // 180 floats per timestep slice, contiguous

typedef __attribute__((ext_vector_type(2))) float f32x2;

__global__ void gather_tab(const float* __restrict__ motion_rots,    // (K,F,6)
                           const float* __restrict__ motion_transls, // (K,F,3)
                           const int*   __restrict__ ts,             // (B)
                           float* __restrict__ tab,                  // ws
                           int F)
{
    const int tid = threadIdx.x;
    if (tid < BB * KK) {
        const int n = tid / KK, k = tid % KK;
        const int t = ts[n];
        const float* rp = motion_rots    + ((size_t)k * F + t) * 6;
        const float* tp = motion_transls + ((size_t)k * F + t) * 3;
        float* base = tab + (size_t)n * SLICE;   // slice n, component-major
        #pragma unroll
        for (int c = 0; c < 6; ++c) base[c * KK + k] = rp[c];
        #pragma unroll
        for (int c = 0; c < 3; ++c) base[(6 + c) * KK + k] = tp[c];
    }
}

__global__ __launch_bounds__(BLK) void motion_fwd(
    const float* __restrict__ motion_coefs, // (G,K)
    const float* __restrict__ means,        // (G,3)
    const float* __restrict__ tab,          // ws: (B, 9, K) slice-contiguous
    float* __restrict__ out,                // (G,B,3)
    int G)
{
    // transposed: wp[kpair][lane] -> b64 accesses are lane-contiguous (2-way
    // bank aliasing = free); invs separate row.
    __shared__ f32x2 wp_lds[KK / 2][64];
    __shared__ float winv_lds[64];

    const int tid  = threadIdx.x;
    const int wq   = __builtin_amdgcn_readfirstlane(tid >> 6);  // wave 0..7
    const int lane = tid & 63;
    const long long p  = (long long)blockIdx.x * GPB + lane;
    const long long pc = p < G ? p : (long long)G - 1;          // clamp

    if (wq == 0) {
        // lane <-> gaussian: softmax weights, unnormalized e^c (no max-sub:
        // inputs ~N(0,1)); 1/sum deferred to the translation only.
        const float4* crow = reinterpret_cast<const float4*>(motion_coefs + pc * KK);
        float s = 0.f;
        #pragma unroll
        for (int u = 0; u < 5; ++u) {
            const float4 v = crow[u];
            const float e0 = __expf(v.x), e1 = __expf(v.y);
            const float e2 = __expf(v.z), e3 = __expf(v.w);
            wp_lds[2*u+0][lane] = (f32x2){e0, e1};
            wp_lds[2*u+1][lane] = (f32x2){e2, e3};
            s += (e0 + e1) + (e2 + e3);
        }
        winv_lds[lane] = __builtin_amdgcn_rcpf(s);
    }
    __syncthreads();

    // every wave pulls its lane's weights (10 x ds_read_b64, in-order)
    f32x2 w2[KK / 2];
    #pragma unroll
    for (int kk = 0; kk < KK / 2; ++kk) w2[kk] = wp_lds[kk][lane];
    const float invs = winv_lds[lane];
    const float mx0 = means[pc*3+0], mx1 = means[pc*3+1], mx2 = means[pc*3+2];

    // this wave's slice: k-reduction (uniform s_load operands) + Gram-Schmidt
    const float* tb = tab + (size_t)wq * SLICE;   // uniform address

    f32x2 acc[9];
    #pragma unroll
    for (int c = 0; c < 9; ++c) acc[c] = (f32x2){0.f, 0.f};

    #pragma unroll
    for (int c = 0; c < 9; ++c) {
        #pragma unroll
        for (int kk = 0; kk < KK / 2; ++kk) {
            // 180 contiguous dwords/slice -> s_load_dwordx16 merging
            const f32x2 t = *reinterpret_cast<const f32x2*>(tb + c * KK + 2 * kk);
            acc[c] += w2[kk] * t;
        }
    }

    float r[9];
    #pragma unroll
    for (int c = 0; c < 9; ++c) r[c] = acc[c].x + acc[c].y;

    const float n1 = __builtin_amdgcn_sqrtf(fmaf(r[0], r[0], fmaf(r[1], r[1], r[2]*r[2])));
    const float i1 = __builtin_amdgcn_rcpf(fmaxf(n1, 1e-12f));
    const float b10 = r[0]*i1, b11 = r[1]*i1, b12 = r[2]*i1;

    const float d  = fmaf(b10, r[3], fmaf(b11, r[4], b12*r[5]));
    const float q0 = fmaf(-d, b10, r[3]);
    const float q1 = fmaf(-d, b11, r[4]);
    const float q2 = fmaf(-d, b12, r[5]);
    const float n2 = __builtin_amdgcn_sqrtf(fmaf(q0, q0, fmaf(q1, q1, q2*q2)));
    const float i2 = __builtin_amdgcn_rcpf(fmaxf(n2, 1e-12f));
    const float b20 = q0*i2, b21 = q1*i2, b22 = q2*i2;

    const float b30 = fmaf(b11, b22, -(b12*b21));
    const float b31 = fmaf(b12, b20, -(b10*b22));
    const float b32 = fmaf(b10, b21, -(b11*b20));

    const float u0 = r[6] * invs;   // transl gets the deferred 1/sum
    const float u1 = r[7] * invs;
    const float u2 = r[8] * invs;

    const float o0 = fmaf(b10, mx0, fmaf(b20, mx1, fmaf(b30, mx2, u0)));
    const float o1 = fmaf(b11, mx0, fmaf(b21, mx1, fmaf(b31, mx2, u1)));
    const float o2 = fmaf(b12, mx0, fmaf(b22, mx1, fmaf(b32, mx2, u2)));

    if (p < G) {
        float* op = out + (size_t)p * (BB*3) + (size_t)wq * 3;
        op[0] = o0; op[1] = o1; op[2] = o2;
    }
}

extern "C" void kernel_launch(void* const* d_in, const int* in_sizes, int n_in,
                              void* d_out, int out_size, void* d_ws, size_t ws_size,
                              hipStream_t stream) {
    const float* motion_rots    = (const float*)d_in[0];
    const float* motion_transls = (const float*)d_in[1];
    const float* motion_coefs   = (const float*)d_in[2];
    const float* means          = (const float*)d_in[3];
    const int*   ts             = (const int*)d_in[4];
    float* out = (float*)d_out;
    float* tab = (float*)d_ws;   // needs BB*SLICE*4 = 5760 B

    const int G = in_sizes[3] / 3;            // means is (G,3)
    const int F = in_sizes[0] / (6 * KK);     // motion_rots is (K,F,6)

    gather_tab<<<1, 192, 0, stream>>>(motion_rots, motion_transls, ts, tab, F);

    const int nblk = (G + GPB - 1) / GPB;     // 64 gaussians per block
    motion_fwd<<<nblk, BLK, 0, stream>>>(motion_coefs, means, tab, out, G);
}